// Round 20
// baseline (103.831 us; speedup 1.0000x reference)
//
#include <hip/hip_runtime.h>
#include <hip/hip_bf16.h>
#include <stdint.h>

// CausalSelfAttention: x[2,2048,1024] -> qkv -> 16-head causal attn -> proj.
// bf16 MFMA pipeline, fp32 accumulation everywhere.
// Round 20 = round-19 + attn strip-PAIRING: each block runs strips (31-p, p)
// sequentially = exactly 33 tile-iters per block -> all 512 blocks identical
// duration, 2 blocks/CU, no makespan tail (r15's permutation balanced totals
// but left each CU finishing on its heaviest block alone).

typedef __attribute__((ext_vector_type(4))) float  f32x4;
typedef __attribute__((ext_vector_type(8))) __bf16 bf16x8;
typedef __attribute__((ext_vector_type(4))) short  s16x4;
typedef __attribute__((ext_vector_type(8))) short  s16x8;

#define MFMA(a, b, c) __builtin_amdgcn_mfma_f32_16x16x32_bf16((a), (b), (c), 0, 0, 0)

// 16x16x16 bf16 MFMA: device pass has it on gfx950; host pass only parses.
#if defined(__HIP_DEVICE_COMPILE__)
#define MFMA16(a, b, c) __builtin_amdgcn_mfma_f32_16x16x16bf16_1k((a), (b), (c), 0, 0, 0)
#else
#define MFMA16(a, b, c) (c)
#endif

// f32 -> bf16 RTNE. Device: native cast so the compiler can fuse pairs into
// v_cvt_pk_bf16_f32. Host: parse-only bit-twiddle equivalent.
__device__ __forceinline__ short f2bf(float x) {
#if defined(__HIP_DEVICE_COMPILE__)
  union { __bf16 b; short s; } u; u.b = (__bf16)x; return u.s;
#else
  union { float f; unsigned u; } v; v.f = x;
  unsigned r = v.u + 0x7FFFu + ((v.u >> 16) & 1u);
  return (short)(r >> 16);
#endif
}

__device__ __forceinline__ void gload16(const void* gptr, void* lptr) {
  __builtin_amdgcn_global_load_lds(
      (const __attribute__((address_space(1))) void*)gptr,
      (__attribute__((address_space(3))) void*)lptr, 16, 0, 0);
}

// ---------------- fused pre-pass: x->bf16 + both weight transposes ----------
// blocks [0,4096): x conv; [4096,7168): W_attn transpose; [7168,8192): W_proj.

__global__ __launch_bounds__(256) void k_prep(const float* __restrict__ x,
                                              const float* __restrict__ Wa,
                                              const float* __restrict__ Wp,
                                              short* __restrict__ x_bf,
                                              short* __restrict__ Wt_a,
                                              short* __restrict__ Wt_p) {
  __shared__ float tile[32][33];
  const int id = blockIdx.x;
  if (id < 4096) {
    const int i = (id * 256 + threadIdx.x) * 4;
    float4 v = *(const float4*)(x + i);
    s16x4 o;
    o[0] = f2bf(v.x); o[1] = f2bf(v.y); o[2] = f2bf(v.z); o[3] = f2bf(v.w);
    *(s16x4*)(x_bf + i) = o;
    return;
  }
  const float* W; short* Wt; int R, C, bx, by;
  if (id < 7168) {
    const int id2 = id - 4096;
    W = Wa; Wt = Wt_a; R = 1024; C = 3072;
    bx = (id2 % 96) * 32; by = (id2 / 96) * 32;
  } else {
    const int id2 = id - 7168;
    W = Wp; Wt = Wt_p; R = 1024; C = 1024;
    bx = (id2 & 31) * 32; by = (id2 >> 5) * 32;
  }
  const int tx = threadIdx.x & 31, ty = threadIdx.x >> 5;  // ty 0..7
#pragma unroll
  for (int i = 0; i < 4; ++i)
    tile[ty + i * 8][tx] = W[(long)(by + ty + i * 8) * C + bx + tx];
  __syncthreads();
#pragma unroll
  for (int i = 0; i < 4; ++i)
    Wt[(long)(bx + ty + i * 8) * R + by + tx] = f2bf(tile[tx][ty + i * 8]);
}

// ---------------- QKV GEMM (2-wave, 64x128/wave): round-18/19 version -------
// 128x128 tile, BK=32, 2 waves (wave w: rows w*64..w*64+63, ALL 128 cols,
// acc[4][8]). TRIPLE-buffered LDS, counted vmcnt(8). Conflict-free swizzled
// LDS layout ([64 lines][64 shorts], slot ((r&1)*4+c)^((r>>1)&7), 2-way max).
// XCD-chunked block swizzle; Q scatter (pre-scaled), K scatter, V via
// LDS-transpose epilogue (contiguous 128 B Vt runs).

__global__ __launch_bounds__(128, 2) void k_gemm_qkv(const short* __restrict__ A,
                                                     const short* __restrict__ Bt,
                                                     const float* __restrict__ bias,
                                                     short* __restrict__ q_out,
                                                     short* __restrict__ k_out,
                                                     short* __restrict__ vt_out) {
  constexpr int K = 1024;
  __shared__ short LDSbuf[24576];     // 48 KB: As = [0,12288), Bs = [12288,24576)
  short* As = LDSbuf;
  short* Bs = LDSbuf + 12288;
  const int tid  = threadIdx.x;       // 0..127
  const int lane = tid & 63;
  const int wave = tid >> 6;          // 0..1
  const int wm = wave * 64;
  const int orig = blockIdx.y * 24 + blockIdx.x;
  const int swz = (orig & 7) * 96 + (orig >> 3);
  const int bxi = swz % 24, byi = swz / 24;
  const int bm = byi * 128, bn = bxi * 128;
  const int v_  = (tid & 7) ^ ((tid >> 3) & 7);
  const int rsw = 2 * (tid >> 3) + (v_ >> 2);
  const int csw = (v_ & 3) * 8;
  const short* Ag = A + (long)(bm + rsw) * K + csw;
  const short* Bg = Bt + (long)(bn + rsw) * K + csw;
  const int fr = lane & 15, fg = lane >> 4;

  f32x4 acc[4][8];
#pragma unroll
  for (int i = 0; i < 4; ++i)
#pragma unroll
    for (int j = 0; j < 8; ++j) acc[i][j] = (f32x4){0.f, 0.f, 0.f, 0.f};

  auto stage = [&](int buf, int kt) {
#pragma unroll
    for (int j = 0; j < 4; ++j) {
      gload16(Ag + kt + (long)(32 * j) * K, &As[buf * 4096 + (tid + 128 * j) * 8]);
      gload16(Bg + kt + (long)(32 * j) * K, &Bs[buf * 4096 + (tid + 128 * j) * 8]);
    }
  };
  const int slotA = (((fr & 1) << 2) + fg) ^ ((fr >> 1) & 7);
  auto compute = [&](int buf) {
    bf16x8 af[4], bfr[8];
    const short* Ar = &As[buf * 4096 + ((wm + fr) >> 1) * 64 + slotA * 8];
    const short* Br = &Bs[buf * 4096 + (fr >> 1) * 64 + slotA * 8];
#pragma unroll
    for (int mi = 0; mi < 4; ++mi) af[mi] = *(const bf16x8*)(Ar + mi * 512);
#pragma unroll
    for (int ni = 0; ni < 8; ++ni) bfr[ni] = *(const bf16x8*)(Br + ni * 512);
#pragma unroll
    for (int mi = 0; mi < 4; ++mi)
#pragma unroll
      for (int ni = 0; ni < 8; ++ni)
        acc[mi][ni] = MFMA(af[mi], bfr[ni], acc[mi][ni]);
  };

  const int NT = K >> 5;
  stage(0, 0);
  stage(1, 32);
  for (int t = 0; t < NT - 1; ++t) {
    asm volatile("s_waitcnt vmcnt(8)" ::: "memory");
    __builtin_amdgcn_s_barrier();
    asm volatile("" ::: "memory");
    if (t + 2 < NT) stage((t + 2) % 3, (t + 2) << 5);
    compute(t % 3);
  }
  asm volatile("s_waitcnt vmcnt(0)" ::: "memory");
  __builtin_amdgcn_s_barrier();
  asm volatile("" ::: "memory");
  compute((NT - 1) % 3);

  const float QSC = 0.125f * 1.44269504088896341f;  // fold attn scale into Q
  const int whichB = bn >> 10;        // block-uniform

  if (whichB == 2) {
    // ---- V epilogue: transpose through LDS, coalesced Vt stores ----
    __syncthreads();
#pragma unroll
    for (int mi = 0; mi < 4; ++mi) {
#pragma unroll
      for (int ni = 0; ni < 8; ++ni) {
        const int cc = ni * 16 + fr;                 // block-local d index
        const float bv = bias[bn + cc];
        const int rr = wm + mi * 16 + fg * 4;        // block-local s index
        s16x4 pv;
#pragma unroll
        for (int r = 0; r < 4; ++r) pv[r] = f2bf(acc[mi][ni][r] + bv);
        *(s16x4*)&LDSbuf[cc * 136 + rr] = pv;        // stride 136 -> 16B rows
      }
    }
    __syncthreads();
    const int bV = bm >> 11, sBase = bm & 2047;
    const int h0v = (bn & 1023) >> 6;
    const int c2 = tid;                              // Vt row 0..127
    const int h2 = h0v + (c2 >> 6), d2 = c2 & 63;
    short* dst = vt_out + ((long)(bV * 16 + h2) * 64 + d2) * 2048 + sBase;
    const short* src = &LDSbuf[c2 * 136];
#pragma unroll
    for (int j = 0; j < 16; ++j)
      *(s16x8*)(dst + j * 8) = *(const s16x8*)(src + j * 8);
  } else {
#pragma unroll
    for (int mi = 0; mi < 4; ++mi) {
#pragma unroll
      for (int ni = 0; ni < 8; ++ni) {
        const int gcol  = bn + ni * 16 + fr;
        const float bv  = bias[gcol];
        const int grow0 = bm + wm + mi * 16 + fg * 4;
        const int e = gcol & 1023;
        const int h = e >> 6, d = e & 63;
#pragma unroll
        for (int r = 0; r < 4; ++r) {
          const int mrow = grow0 + r;
          const int b = mrow >> 11, s = mrow & 2047;
          const float av = acc[mi][ni][r] + bv;
          if (whichB == 0)
            q_out[((long)(b * 16 + h) * 2048 + s) * 64 + d] = f2bf(av * QSC);
          else
            k_out[((long)(b * 16 + h) * 2048 + s) * 64 + d] = f2bf(av);
        }
      }
    }
  }
}

// ---------------- proj GEMM (4-wave, 64x64/wave): round-15 version ----------
// 128x128 tile, BK=32, 4 waves. Triple-buffered LDS, counted vmcnt(4).
// Conflict-free swizzled LDS layout. fp32 row-major output.

__global__ __launch_bounds__(256) void k_gemm_proj(const short* __restrict__ A,
                                                   const short* __restrict__ Bt,
                                                   const float* __restrict__ bias,
                                                   float* __restrict__ c_out) {
  constexpr int K = 1024;
  constexpr int N = 1024;
  __shared__ short LDSbuf[24576];
  short* As = LDSbuf;
  short* Bs = LDSbuf + 12288;
  const int tid  = threadIdx.x;
  const int lane = tid & 63;
  const int wave = tid >> 6;
  const int wm = (wave >> 1) * 64, wn = (wave & 1) * 64;
  const int bm = blockIdx.y * 128, bn = blockIdx.x * 128;
  const int v_  = (tid & 7) ^ ((tid >> 3) & 7);
  const int rsw = 2 * (tid >> 3) + (v_ >> 2);
  const int csw = (v_ & 3) * 8;
  const short* Ag = A + (long)(bm + rsw) * K + csw;
  const short* Bg = Bt + (long)(bn + rsw) * K + csw;
  const int fr = lane & 15, fg = lane >> 4;

  f32x4 acc[4][4];
#pragma unroll
  for (int i = 0; i < 4; ++i)
#pragma unroll
    for (int j = 0; j < 4; ++j) acc[i][j] = (f32x4){0.f, 0.f, 0.f, 0.f};

  auto stage = [&](int buf, int kt) {
    gload16(Ag + kt, &As[buf * 4096 + tid * 8]);
    gload16(Ag + kt + 64 * K, &As[buf * 4096 + 2048 + tid * 8]);
    gload16(Bg + kt, &Bs[buf * 4096 + tid * 8]);
    gload16(Bg + kt + 64 * K, &Bs[buf * 4096 + 2048 + tid * 8]);
  };
  const int slotA = (((fr & 1) << 2) + fg) ^ ((fr >> 1) & 7);
  auto compute = [&](int buf) {
    bf16x8 af[4], bfr[4];
    const short* Ar = &As[buf * 4096 + ((wm + fr) >> 1) * 64 + slotA * 8];
    const short* Br = &Bs[buf * 4096 + ((wn + fr) >> 1) * 64 + slotA * 8];
#pragma unroll
    for (int mi = 0; mi < 4; ++mi) af[mi] = *(const bf16x8*)(Ar + mi * 512);
#pragma unroll
    for (int ni = 0; ni < 4; ++ni) bfr[ni] = *(const bf16x8*)(Br + ni * 512);
#pragma unroll
    for (int mi = 0; mi < 4; ++mi)
#pragma unroll
      for (int ni = 0; ni < 4; ++ni)
        acc[mi][ni] = MFMA(af[mi], bfr[ni], acc[mi][ni]);
  };

  const int NT = K >> 5;
  stage(0, 0);
  stage(1, 32);
  for (int t = 0; t < NT - 1; ++t) {
    asm volatile("s_waitcnt vmcnt(4)" ::: "memory");
    __builtin_amdgcn_s_barrier();
    asm volatile("" ::: "memory");
    if (t + 2 < NT) stage((t + 2) % 3, (t + 2) << 5);
    compute(t % 3);
  }
  asm volatile("s_waitcnt vmcnt(0)" ::: "memory");
  __builtin_amdgcn_s_barrier();
  asm volatile("" ::: "memory");
  compute((NT - 1) % 3);

#pragma unroll
  for (int mi = 0; mi < 4; ++mi) {
#pragma unroll
    for (int ni = 0; ni < 4; ++ni) {
      const int gcol  = bn + wn + ni * 16 + fr;
      const float bv  = bias[gcol];
      const int grow0 = bm + wm + mi * 16 + fg * 4;
#pragma unroll
      for (int r = 0; r < 4; ++r)
        c_out[(long)(grow0 + r) * N + gcol] = acc[mi][ni][r] + bv;
    }
  }
}

// ---------------- causal flash attention (strip-paired) ---------------------
// grid (bh=32, p=16), 256-thread blocks (4 waves x 16 q-rows). Each block
// processes strips 31-p then p: total = (32-p) + (p+1) = 33 tile-iters for
// EVERY block -> 512 identical-duration blocks, 2/CU, zero makespan tail.
// Inner loop verbatim round-15/19: K/V tiles (64 keys) in XOR-swizzled LDS,
// double-buffered global_load_lds; swapped QK^T (mfma(K,Q)) puts P in the
// 16x16x16 B-operand layout -> PV from registers; Q pre-scaled by
// 0.125*log2e (exp2 domain); MAX-FREE softmax; l-sum on the MFMA pipe.

__global__ __launch_bounds__(256, 2) void k_attn(const short* __restrict__ Qb,
                                                 const short* __restrict__ Kb,
                                                 const short* __restrict__ Vt,
                                                 short* __restrict__ Y) {
  __shared__ short smem[2][2][4096];   // [buf][0=K,1=V][64 rows][64 shorts]
  const int bh = blockIdx.x;
  const int p = blockIdx.y;            // 0..15
  const int b = bh >> 4, h = bh & 15;
  const int tid = threadIdx.x;
  const int w = tid >> 6, lane = tid & 63;
  const int ql = lane & 15, g = lane >> 4;
  const short* Kp = Kb + (long)bh * 2048 * 64;
  const short* Vp = Vt + (long)bh * 64 * 2048;
  const int sr_ = tid >> 3, sj_ = tid & 7;

  s16x4 ones;
  ones[0] = ones[1] = ones[2] = ones[3] = (short)0x3F80;  // bf16 1.0

  for (int ss = 0; ss < 2; ++ss) {
    const int strip = ss == 0 ? (31 - p) : p;   // heavy strip first
    const int qw0 = strip * 64;
    const short* Qp = Qb + ((long)bh * 2048 + qw0 + w * 16) * 64;
    const bf16x8 qf0 = *(const bf16x8*)(Qp + ql * 64 + g * 8);
    const bf16x8 qf1 = *(const bf16x8*)(Qp + ql * 64 + 32 + g * 8);

    f32x4 o[4];
#pragma unroll
    for (int df = 0; df < 4; ++df) o[df] = (f32x4){0.f, 0.f, 0.f, 0.f};
    f32x4 o_l = (f32x4){0.f, 0.f, 0.f, 0.f};   // row-sum accumulator (l)
    const int nt = strip + 1;

    if (ss) __syncthreads();          // prev strip's epilogue LDS reads done
    {  // prologue stage of tile 0
#pragma unroll
      for (int j = 0; j < 2; ++j) {
        const int r = j * 32 + sr_;
        const int c = sj_ ^ (r & 7);
        gload16(Kp + (long)r * 64 + c * 8, &smem[0][0][j * 2048 + tid * 8]);
        gload16(Vp + (long)r * 2048 + c * 8, &smem[0][1][j * 2048 + tid * 8]);
      }
    }

    for (int t = 0; t < nt; ++t) {
      const int cur = t & 1;
      __syncthreads();                // waits own vmcnt -> buf[cur] ready
      if (t + 1 < nt) {               // next-tile stage, drains at next barrier
        const int k0n = (t + 1) * 64;
#pragma unroll
        for (int j = 0; j < 2; ++j) {
          const int r = j * 32 + sr_;
          const int c = sj_ ^ (r & 7);
          gload16(Kp + (long)(k0n + r) * 64 + c * 8, &smem[cur ^ 1][0][j * 2048 + tid * 8]);
          gload16(Vp + (long)r * 2048 + k0n + c * 8, &smem[cur ^ 1][1][j * 2048 + tid * 8]);
        }
      }
      const short* Kl = &smem[cur][0][0];
      const short* Vl = &smem[cur][1][0];
      const bool diag = (t == strip);

      // ---- QK^T from LDS (swizzled b128 reads); scores exp2-scaled ----
      float z[16];
      __builtin_amdgcn_s_setprio(1);
#pragma unroll
      for (int kf = 0; kf < 4; ++kf) {
        if (!diag || kf <= w) {
          const int r = kf * 16 + ql;
          const bf16x8 ka = *(const bf16x8*)(Kl + r * 64 + ((g ^ (r & 7)) * 8));
          const bf16x8 kb = *(const bf16x8*)(Kl + r * 64 + (((4 + g) ^ (r & 7)) * 8));
          f32x4 zz = (f32x4){0.f, 0.f, 0.f, 0.f};
          zz = MFMA(ka, qf0, zz);     // S^T[k][q], d 0..31
          zz = MFMA(kb, qf1, zz);     // += d 32..63
          if (diag && kf == w) {      // diagonal 16x16 block: per-element mask
#pragma unroll
            for (int r4 = 0; r4 < 4; ++r4)
              z[kf * 4 + r4] = (g * 4 + r4 <= ql) ? zz[r4] : -3.0e38f;
          } else {
#pragma unroll
            for (int r4 = 0; r4 < 4; ++r4) z[kf * 4 + r4] = zz[r4];
          }
        } else {
#pragma unroll
          for (int r4 = 0; r4 < 4; ++r4) z[kf * 4 + r4] = -3.0e38f;
        }
      }
      __builtin_amdgcn_s_setprio(0);

      // ---- P = exp2(z) straight into bf16 fragments; PV + l via MFMA ----
      __builtin_amdgcn_s_setprio(1);
#pragma unroll
      for (int kf = 0; kf < 4; ++kf) {
        if (!diag || kf <= w) {
          s16x4 pk;
          pk[0] = f2bf(exp2f(z[kf * 4 + 0]));
          pk[1] = f2bf(exp2f(z[kf * 4 + 1]));
          pk[2] = f2bf(exp2f(z[kf * 4 + 2]));
          pk[3] = f2bf(exp2f(z[kf * 4 + 3]));
          o_l = MFMA16(ones, pk, o_l);     // row-sum on the matrix pipe
#pragma unroll
          for (int df = 0; df < 4; ++df) {
            const int d = df * 16 + ql;
            const int c = kf * 2 + (g >> 1);
            const s16x4 vk = *(const s16x4*)(Vl + d * 64 + ((c ^ (d & 7)) * 8) + (g & 1) * 4);
            o[df] = MFMA16(vk, pk, o[df]); // O^T[d][q]
          }
        }
      }
      __builtin_amdgcn_s_setprio(0);
    }

    // ---- epilogue: divide, transpose via LDS overlay, coalesced store ----
    __syncthreads();                  // all waves done reading K/V buffers
    float* ot = (float*)&smem[0][0][0] + w * 1040; // per-wave 16x65 floats
    const float linv = 1.f / o_l[0];  // every lane holds l for its q=ql
#pragma unroll
    for (int df = 0; df < 4; ++df)
#pragma unroll
      for (int r = 0; r < 4; ++r)
        ot[ql * 65 + df * 16 + g * 4 + r] = o[df][r] * linv;
    const int q2 = lane >> 2, c4 = (lane & 3) * 16;
    short* Yp = Y + ((long)(b * 2048 + qw0 + w * 16 + q2)) * 1024 + h * 64 + c4;
    s16x8 y0, y1;
#pragma unroll
    for (int j = 0; j < 8; ++j) {
      y0[j] = f2bf(ot[q2 * 65 + c4 + j]);
      y1[j] = f2bf(ot[q2 * 65 + c4 + 8 + j]);
    }
    *(s16x8*)Yp = y0;
    *((s16x8*)(Yp + 8)) = y1;
  }
}

// ---------------- launch ----------------

extern "C" void kernel_launch(void* const* d_in, const int* in_sizes, int n_in,
                              void* d_out, int out_size, void* d_ws, size_t ws_size,
                              hipStream_t stream) {
  const float* x      = (const float*)d_in[0];
  const float* W_attn = (const float*)d_in[1];
  const float* b_attn = (const float*)d_in[2];
  const float* W_proj = (const float*)d_in[3];
  const float* b_proj = (const float*)d_in[4];
  float* out = (float*)d_out;

  char* ws = (char*)d_ws;
  short* x_bf = (short*)(ws);                    //  8 MB  [4096][1024]
  short* Wt_a = (short*)(ws + 8388608);          //  6 MB  [3072][1024]
  short* Wt_p = (short*)(ws + 14680064);         //  2 MB  [1024][1024]
  short* Qb   = (short*)(ws + 16777216);         //  8 MB  [2,16,2048,64]
  short* Kb   = (short*)(ws + 25165824);         //  8 MB  [2,16,2048,64]
  short* Vtb  = (short*)(ws + 33554432);         //  8 MB  [2,16,64,2048]
  short* y_bf = (short*)(ws + 41943040);         //  8 MB  [4096][1024]

  k_prep<<<8192, 256, 0, stream>>>(x, W_attn, W_proj, x_bf, Wt_a, Wt_p);
  k_gemm_qkv<<<dim3(24, 32), 128, 0, stream>>>(x_bf, Wt_a, b_attn, Qb, Kb, Vtb);
  k_attn<<<dim3(32, 16), 256, 0, stream>>>(Qb, Kb, Vtb, y_bf);
  k_gemm_proj<<<dim3(8, 32), 256, 0, stream>>>(y_bf, Wt_p, b_proj, out);
}

// Round 21
// 102.525 us; speedup vs baseline: 1.0127x; 1.0127x over previous
//
#include <hip/hip_runtime.h>
#include <hip/hip_bf16.h>
#include <stdint.h>

// CausalSelfAttention: x[2,2048,1024] -> qkv -> 16-head causal attn -> proj.
// bf16 MFMA pipeline, fp32 accumulation everywhere.
// Round 21 = verbatim revert to round-19 (verified best, 102.6 us).
// r20 post-mortem: strip-pairing halved the attn grid to 2 blocks/CU ->
// 8 waves/CU (Occ 17%) and serialized each block's two strips; the tail it
// removed (~10%) cost ~50% TLP. r19's 1024-block balanced-permutation grid
// (4 blocks/CU, 16 waves/CU) is the measured optimum.
// qkv is LDS-read-pipe bound (~61 of ~85 B/cyc b128 ceiling per CU) -- the
// remaining levers would need 256^2-class register tiles, which regressed
// twice at this problem shape (grid coverage / vmcnt drain).

typedef __attribute__((ext_vector_type(4))) float  f32x4;
typedef __attribute__((ext_vector_type(8))) __bf16 bf16x8;
typedef __attribute__((ext_vector_type(4))) short  s16x4;
typedef __attribute__((ext_vector_type(8))) short  s16x8;

#define MFMA(a, b, c) __builtin_amdgcn_mfma_f32_16x16x32_bf16((a), (b), (c), 0, 0, 0)

// 16x16x16 bf16 MFMA: device pass has it on gfx950; host pass only parses.
#if defined(__HIP_DEVICE_COMPILE__)
#define MFMA16(a, b, c) __builtin_amdgcn_mfma_f32_16x16x16bf16_1k((a), (b), (c), 0, 0, 0)
#else
#define MFMA16(a, b, c) (c)
#endif

// f32 -> bf16 RTNE. Device: native cast so the compiler can fuse pairs into
// v_cvt_pk_bf16_f32. Host: parse-only bit-twiddle equivalent.
__device__ __forceinline__ short f2bf(float x) {
#if defined(__HIP_DEVICE_COMPILE__)
  union { __bf16 b; short s; } u; u.b = (__bf16)x; return u.s;
#else
  union { float f; unsigned u; } v; v.f = x;
  unsigned r = v.u + 0x7FFFu + ((v.u >> 16) & 1u);
  return (short)(r >> 16);
#endif
}

__device__ __forceinline__ void gload16(const void* gptr, void* lptr) {
  __builtin_amdgcn_global_load_lds(
      (const __attribute__((address_space(1))) void*)gptr,
      (__attribute__((address_space(3))) void*)lptr, 16, 0, 0);
}

// ---------------- fused pre-pass: x->bf16 + both weight transposes ----------
// blocks [0,4096): x conv; [4096,7168): W_attn transpose; [7168,8192): W_proj.

__global__ __launch_bounds__(256) void k_prep(const float* __restrict__ x,
                                              const float* __restrict__ Wa,
                                              const float* __restrict__ Wp,
                                              short* __restrict__ x_bf,
                                              short* __restrict__ Wt_a,
                                              short* __restrict__ Wt_p) {
  __shared__ float tile[32][33];
  const int id = blockIdx.x;
  if (id < 4096) {
    const int i = (id * 256 + threadIdx.x) * 4;
    float4 v = *(const float4*)(x + i);
    s16x4 o;
    o[0] = f2bf(v.x); o[1] = f2bf(v.y); o[2] = f2bf(v.z); o[3] = f2bf(v.w);
    *(s16x4*)(x_bf + i) = o;
    return;
  }
  const float* W; short* Wt; int R, C, bx, by;
  if (id < 7168) {
    const int id2 = id - 4096;
    W = Wa; Wt = Wt_a; R = 1024; C = 3072;
    bx = (id2 % 96) * 32; by = (id2 / 96) * 32;
  } else {
    const int id2 = id - 7168;
    W = Wp; Wt = Wt_p; R = 1024; C = 1024;
    bx = (id2 & 31) * 32; by = (id2 >> 5) * 32;
  }
  const int tx = threadIdx.x & 31, ty = threadIdx.x >> 5;  // ty 0..7
#pragma unroll
  for (int i = 0; i < 4; ++i)
    tile[ty + i * 8][tx] = W[(long)(by + ty + i * 8) * C + bx + tx];
  __syncthreads();
#pragma unroll
  for (int i = 0; i < 4; ++i)
    Wt[(long)(bx + ty + i * 8) * R + by + tx] = f2bf(tile[tx][ty + i * 8]);
}

// ---------------- QKV GEMM (2-wave, 64x128/wave): round-18/19 version -------
// 128x128 tile, BK=32, 2 waves (wave w: rows w*64..w*64+63, ALL 128 cols,
// acc[4][8]). TRIPLE-buffered LDS, counted vmcnt(8). Conflict-free swizzled
// LDS layout ([64 lines][64 shorts], slot ((r&1)*4+c)^((r>>1)&7), 2-way max).
// XCD-chunked block swizzle; Q scatter (pre-scaled), K scatter, V via
// LDS-transpose epilogue (contiguous 128 B Vt runs).

__global__ __launch_bounds__(128, 2) void k_gemm_qkv(const short* __restrict__ A,
                                                     const short* __restrict__ Bt,
                                                     const float* __restrict__ bias,
                                                     short* __restrict__ q_out,
                                                     short* __restrict__ k_out,
                                                     short* __restrict__ vt_out) {
  constexpr int K = 1024;
  __shared__ short LDSbuf[24576];     // 48 KB: As = [0,12288), Bs = [12288,24576)
  short* As = LDSbuf;
  short* Bs = LDSbuf + 12288;
  const int tid  = threadIdx.x;       // 0..127
  const int lane = tid & 63;
  const int wave = tid >> 6;          // 0..1
  const int wm = wave * 64;
  const int orig = blockIdx.y * 24 + blockIdx.x;
  const int swz = (orig & 7) * 96 + (orig >> 3);
  const int bxi = swz % 24, byi = swz / 24;
  const int bm = byi * 128, bn = bxi * 128;
  const int v_  = (tid & 7) ^ ((tid >> 3) & 7);
  const int rsw = 2 * (tid >> 3) + (v_ >> 2);
  const int csw = (v_ & 3) * 8;
  const short* Ag = A + (long)(bm + rsw) * K + csw;
  const short* Bg = Bt + (long)(bn + rsw) * K + csw;
  const int fr = lane & 15, fg = lane >> 4;

  f32x4 acc[4][8];
#pragma unroll
  for (int i = 0; i < 4; ++i)
#pragma unroll
    for (int j = 0; j < 8; ++j) acc[i][j] = (f32x4){0.f, 0.f, 0.f, 0.f};

  auto stage = [&](int buf, int kt) {
#pragma unroll
    for (int j = 0; j < 4; ++j) {
      gload16(Ag + kt + (long)(32 * j) * K, &As[buf * 4096 + (tid + 128 * j) * 8]);
      gload16(Bg + kt + (long)(32 * j) * K, &Bs[buf * 4096 + (tid + 128 * j) * 8]);
    }
  };
  const int slotA = (((fr & 1) << 2) + fg) ^ ((fr >> 1) & 7);
  auto compute = [&](int buf) {
    bf16x8 af[4], bfr[8];
    const short* Ar = &As[buf * 4096 + ((wm + fr) >> 1) * 64 + slotA * 8];
    const short* Br = &Bs[buf * 4096 + (fr >> 1) * 64 + slotA * 8];
#pragma unroll
    for (int mi = 0; mi < 4; ++mi) af[mi] = *(const bf16x8*)(Ar + mi * 512);
#pragma unroll
    for (int ni = 0; ni < 8; ++ni) bfr[ni] = *(const bf16x8*)(Br + ni * 512);
#pragma unroll
    for (int mi = 0; mi < 4; ++mi)
#pragma unroll
      for (int ni = 0; ni < 8; ++ni)
        acc[mi][ni] = MFMA(af[mi], bfr[ni], acc[mi][ni]);
  };

  const int NT = K >> 5;
  stage(0, 0);
  stage(1, 32);
  for (int t = 0; t < NT - 1; ++t) {
    asm volatile("s_waitcnt vmcnt(8)" ::: "memory");
    __builtin_amdgcn_s_barrier();
    asm volatile("" ::: "memory");
    if (t + 2 < NT) stage((t + 2) % 3, (t + 2) << 5);
    compute(t % 3);
  }
  asm volatile("s_waitcnt vmcnt(0)" ::: "memory");
  __builtin_amdgcn_s_barrier();
  asm volatile("" ::: "memory");
  compute((NT - 1) % 3);

  const float QSC = 0.125f * 1.44269504088896341f;  // fold attn scale into Q
  const int whichB = bn >> 10;        // block-uniform

  if (whichB == 2) {
    // ---- V epilogue: transpose through LDS, coalesced Vt stores ----
    __syncthreads();
#pragma unroll
    for (int mi = 0; mi < 4; ++mi) {
#pragma unroll
      for (int ni = 0; ni < 8; ++ni) {
        const int cc = ni * 16 + fr;                 // block-local d index
        const float bv = bias[bn + cc];
        const int rr = wm + mi * 16 + fg * 4;        // block-local s index
        s16x4 pv;
#pragma unroll
        for (int r = 0; r < 4; ++r) pv[r] = f2bf(acc[mi][ni][r] + bv);
        *(s16x4*)&LDSbuf[cc * 136 + rr] = pv;        // stride 136 -> 16B rows
      }
    }
    __syncthreads();
    const int bV = bm >> 11, sBase = bm & 2047;
    const int h0v = (bn & 1023) >> 6;
    const int c2 = tid;                              // Vt row 0..127
    const int h2 = h0v + (c2 >> 6), d2 = c2 & 63;
    short* dst = vt_out + ((long)(bV * 16 + h2) * 64 + d2) * 2048 + sBase;
    const short* src = &LDSbuf[c2 * 136];
#pragma unroll
    for (int j = 0; j < 16; ++j)
      *(s16x8*)(dst + j * 8) = *(const s16x8*)(src + j * 8);
  } else {
#pragma unroll
    for (int mi = 0; mi < 4; ++mi) {
#pragma unroll
      for (int ni = 0; ni < 8; ++ni) {
        const int gcol  = bn + ni * 16 + fr;
        const float bv  = bias[gcol];
        const int grow0 = bm + wm + mi * 16 + fg * 4;
        const int e = gcol & 1023;
        const int h = e >> 6, d = e & 63;
#pragma unroll
        for (int r = 0; r < 4; ++r) {
          const int mrow = grow0 + r;
          const int b = mrow >> 11, s = mrow & 2047;
          const float av = acc[mi][ni][r] + bv;
          if (whichB == 0)
            q_out[((long)(b * 16 + h) * 2048 + s) * 64 + d] = f2bf(av * QSC);
          else
            k_out[((long)(b * 16 + h) * 2048 + s) * 64 + d] = f2bf(av);
        }
      }
    }
  }
}

// ---------------- proj GEMM (4-wave, 64x64/wave): round-15 version ----------
// 128x128 tile, BK=32, 4 waves. Triple-buffered LDS, counted vmcnt(4).
// Conflict-free swizzled LDS layout. fp32 row-major output.

__global__ __launch_bounds__(256) void k_gemm_proj(const short* __restrict__ A,
                                                   const short* __restrict__ Bt,
                                                   const float* __restrict__ bias,
                                                   float* __restrict__ c_out) {
  constexpr int K = 1024;
  constexpr int N = 1024;
  __shared__ short LDSbuf[24576];
  short* As = LDSbuf;
  short* Bs = LDSbuf + 12288;
  const int tid  = threadIdx.x;
  const int lane = tid & 63;
  const int wave = tid >> 6;
  const int wm = (wave >> 1) * 64, wn = (wave & 1) * 64;
  const int bm = blockIdx.y * 128, bn = blockIdx.x * 128;
  const int v_  = (tid & 7) ^ ((tid >> 3) & 7);
  const int rsw = 2 * (tid >> 3) + (v_ >> 2);
  const int csw = (v_ & 3) * 8;
  const short* Ag = A + (long)(bm + rsw) * K + csw;
  const short* Bg = Bt + (long)(bn + rsw) * K + csw;
  const int fr = lane & 15, fg = lane >> 4;

  f32x4 acc[4][4];
#pragma unroll
  for (int i = 0; i < 4; ++i)
#pragma unroll
    for (int j = 0; j < 4; ++j) acc[i][j] = (f32x4){0.f, 0.f, 0.f, 0.f};

  auto stage = [&](int buf, int kt) {
    gload16(Ag + kt, &As[buf * 4096 + tid * 8]);
    gload16(Ag + kt + 64 * K, &As[buf * 4096 + 2048 + tid * 8]);
    gload16(Bg + kt, &Bs[buf * 4096 + tid * 8]);
    gload16(Bg + kt + 64 * K, &Bs[buf * 4096 + 2048 + tid * 8]);
  };
  const int slotA = (((fr & 1) << 2) + fg) ^ ((fr >> 1) & 7);
  auto compute = [&](int buf) {
    bf16x8 af[4], bfr[4];
    const short* Ar = &As[buf * 4096 + ((wm + fr) >> 1) * 64 + slotA * 8];
    const short* Br = &Bs[buf * 4096 + ((wn + fr) >> 1) * 64 + slotA * 8];
#pragma unroll
    for (int mi = 0; mi < 4; ++mi) af[mi] = *(const bf16x8*)(Ar + mi * 512);
#pragma unroll
    for (int ni = 0; ni < 4; ++ni) bfr[ni] = *(const bf16x8*)(Br + ni * 512);
#pragma unroll
    for (int mi = 0; mi < 4; ++mi)
#pragma unroll
      for (int ni = 0; ni < 4; ++ni)
        acc[mi][ni] = MFMA(af[mi], bfr[ni], acc[mi][ni]);
  };

  const int NT = K >> 5;
  stage(0, 0);
  stage(1, 32);
  for (int t = 0; t < NT - 1; ++t) {
    asm volatile("s_waitcnt vmcnt(4)" ::: "memory");
    __builtin_amdgcn_s_barrier();
    asm volatile("" ::: "memory");
    if (t + 2 < NT) stage((t + 2) % 3, (t + 2) << 5);
    compute(t % 3);
  }
  asm volatile("s_waitcnt vmcnt(0)" ::: "memory");
  __builtin_amdgcn_s_barrier();
  asm volatile("" ::: "memory");
  compute((NT - 1) % 3);

#pragma unroll
  for (int mi = 0; mi < 4; ++mi) {
#pragma unroll
    for (int ni = 0; ni < 4; ++ni) {
      const int gcol  = bn + wn + ni * 16 + fr;
      const float bv  = bias[gcol];
      const int grow0 = bm + wm + mi * 16 + fg * 4;
#pragma unroll
      for (int r = 0; r < 4; ++r)
        c_out[(long)(grow0 + r) * N + gcol] = acc[mi][ni][r] + bv;
    }
  }
}

// ---------------- causal flash attention (round-15/19 config) ---------------
// grid (bh=32, y=32), 256-thread blocks (4 waves x 16 q-rows). Balanced strip
// permutation: CU c receives y in {a, a+8, a+16, a+24}; strip(y=8q+r) =
// {31-r, 16+r, 15-r, r} -> each CU's four strips sum to exactly 66 tile-units
// (perfect makespan balance). XCD locality: orig%8 = bh%8 -> 4 heads/XCD.
// K/V tiles (64 keys) in XOR-swizzled LDS, double-buffered global_load_lds.
// Swapped QK^T (mfma(K,Q)) puts P in the 16x16x16 B-operand layout -> PV from
// registers. Q pre-scaled by 0.125*log2e (exp2 domain). MAX-FREE softmax.
// l-sum on the MFMA pipe via ones-fragment.

__global__ __launch_bounds__(256, 4) void k_attn(const short* __restrict__ Qb,
                                                 const short* __restrict__ Kb,
                                                 const short* __restrict__ Vt,
                                                 short* __restrict__ Y) {
  __shared__ short smem[2][2][4096];   // [buf][0=K,1=V][64 rows][64 shorts]
  const int bh = blockIdx.x;
  const int yq = blockIdx.y >> 3, yr = blockIdx.y & 7;
  const int strip = (yq == 0) ? (31 - yr) : (yq == 1) ? (16 + yr)
                  : (yq == 2) ? (15 - yr) : yr;      // balanced permutation
  const int qw0 = strip * 64;
  const int b = bh >> 4, h = bh & 15;
  const int tid = threadIdx.x;
  const int w = tid >> 6, lane = tid & 63;
  const int ql = lane & 15, g = lane >> 4;
  const short* Kp = Kb + (long)bh * 2048 * 64;
  const short* Vp = Vt + (long)bh * 64 * 2048;
  const short* Qp = Qb + ((long)bh * 2048 + qw0 + w * 16) * 64;

  const bf16x8 qf0 = *(const bf16x8*)(Qp + ql * 64 + g * 8);
  const bf16x8 qf1 = *(const bf16x8*)(Qp + ql * 64 + 32 + g * 8);

  const int sr_ = tid >> 3, sj_ = tid & 7;

  s16x4 ones;
  ones[0] = ones[1] = ones[2] = ones[3] = (short)0x3F80;  // bf16 1.0

  f32x4 o[4];
#pragma unroll
  for (int df = 0; df < 4; ++df) o[df] = (f32x4){0.f, 0.f, 0.f, 0.f};
  f32x4 o_l = (f32x4){0.f, 0.f, 0.f, 0.f};   // row-sum accumulator (l)
  const int nt = strip + 1;

  {  // prologue stage of tile 0
#pragma unroll
    for (int j = 0; j < 2; ++j) {
      const int r = j * 32 + sr_;
      const int c = sj_ ^ (r & 7);
      gload16(Kp + (long)r * 64 + c * 8, &smem[0][0][j * 2048 + tid * 8]);
      gload16(Vp + (long)r * 2048 + c * 8, &smem[0][1][j * 2048 + tid * 8]);
    }
  }

  for (int t = 0; t < nt; ++t) {
    const int cur = t & 1;
    __syncthreads();                  // waits own vmcnt -> buf[cur] ready, prev reads done
    if (t + 1 < nt) {                 // issue next-tile stage; lands before next barrier
      const int k0n = (t + 1) * 64;
#pragma unroll
      for (int j = 0; j < 2; ++j) {
        const int r = j * 32 + sr_;
        const int c = sj_ ^ (r & 7);
        gload16(Kp + (long)(k0n + r) * 64 + c * 8, &smem[cur ^ 1][0][j * 2048 + tid * 8]);
        gload16(Vp + (long)r * 2048 + k0n + c * 8, &smem[cur ^ 1][1][j * 2048 + tid * 8]);
      }
    }
    const short* Kl = &smem[cur][0][0];
    const short* Vl = &smem[cur][1][0];
    const bool diag = (t == strip);

    // ---- QK^T from LDS (swizzled b128 reads); scores already exp2-scaled ----
    float z[16];
    __builtin_amdgcn_s_setprio(1);
#pragma unroll
    for (int kf = 0; kf < 4; ++kf) {
      if (!diag || kf <= w) {
        const int r = kf * 16 + ql;
        const bf16x8 ka = *(const bf16x8*)(Kl + r * 64 + ((g ^ (r & 7)) * 8));
        const bf16x8 kb = *(const bf16x8*)(Kl + r * 64 + (((4 + g) ^ (r & 7)) * 8));
        f32x4 zz = (f32x4){0.f, 0.f, 0.f, 0.f};
        zz = MFMA(ka, qf0, zz);       // S^T[k][q], d 0..31
        zz = MFMA(kb, qf1, zz);       // += d 32..63
        if (diag && kf == w) {        // diagonal 16x16 block: per-element mask
#pragma unroll
          for (int r4 = 0; r4 < 4; ++r4)
            z[kf * 4 + r4] = (g * 4 + r4 <= ql) ? zz[r4] : -3.0e38f;
        } else {
#pragma unroll
          for (int r4 = 0; r4 < 4; ++r4) z[kf * 4 + r4] = zz[r4];
        }
      } else {
#pragma unroll
        for (int r4 = 0; r4 < 4; ++r4) z[kf * 4 + r4] = -3.0e38f;
      }
    }
    __builtin_amdgcn_s_setprio(0);

    // ---- P = exp2(z) straight into bf16 fragments; PV + l via MFMA ----
    // (max-free: exp2f(-3e38) == 0 handles the mask)
    __builtin_amdgcn_s_setprio(1);
#pragma unroll
    for (int kf = 0; kf < 4; ++kf) {
      if (!diag || kf <= w) {
        s16x4 pk;
        pk[0] = f2bf(exp2f(z[kf * 4 + 0]));
        pk[1] = f2bf(exp2f(z[kf * 4 + 1]));
        pk[2] = f2bf(exp2f(z[kf * 4 + 2]));
        pk[3] = f2bf(exp2f(z[kf * 4 + 3]));
        o_l = MFMA16(ones, pk, o_l);       // row-sum on the matrix pipe
#pragma unroll
        for (int df = 0; df < 4; ++df) {
          const int d = df * 16 + ql;
          const int c = kf * 2 + (g >> 1);
          const s16x4 vk = *(const s16x4*)(Vl + d * 64 + ((c ^ (d & 7)) * 8) + (g & 1) * 4);
          o[df] = MFMA16(vk, pk, o[df]);   // O^T[d][q]
        }
      }
    }
    __builtin_amdgcn_s_setprio(0);
  }

  // ---- epilogue: divide, transpose via LDS overlay, coalesced store ----
  __syncthreads();                    // all waves done reading K/V buffers
  float* ot = (float*)&smem[0][0][0] + w * 1040;   // per-wave 16x65 floats
  const float linv = 1.f / o_l[0];    // every lane holds l for its q=ql
#pragma unroll
  for (int df = 0; df < 4; ++df)
#pragma unroll
    for (int r = 0; r < 4; ++r)
      ot[ql * 65 + df * 16 + g * 4 + r] = o[df][r] * linv;
  const int q2 = lane >> 2, c4 = (lane & 3) * 16;
  short* Yp = Y + ((long)(b * 2048 + qw0 + w * 16 + q2)) * 1024 + h * 64 + c4;
  s16x8 y0, y1;
#pragma unroll
  for (int j = 0; j < 8; ++j) {
    y0[j] = f2bf(ot[q2 * 65 + c4 + j]);
    y1[j] = f2bf(ot[q2 * 65 + c4 + 8 + j]);
  }
  *(s16x8*)Yp = y0;
  *((s16x8*)(Yp + 8)) = y1;
}

// ---------------- launch ----------------

extern "C" void kernel_launch(void* const* d_in, const int* in_sizes, int n_in,
                              void* d_out, int out_size, void* d_ws, size_t ws_size,
                              hipStream_t stream) {
  const float* x      = (const float*)d_in[0];
  const float* W_attn = (const float*)d_in[1];
  const float* b_attn = (const float*)d_in[2];
  const float* W_proj = (const float*)d_in[3];
  const float* b_proj = (const float*)d_in[4];
  float* out = (float*)d_out;

  char* ws = (char*)d_ws;
  short* x_bf = (short*)(ws);                    //  8 MB  [4096][1024]
  short* Wt_a = (short*)(ws + 8388608);          //  6 MB  [3072][1024]
  short* Wt_p = (short*)(ws + 14680064);         //  2 MB  [1024][1024]
  short* Qb   = (short*)(ws + 16777216);         //  8 MB  [2,16,2048,64]
  short* Kb   = (short*)(ws + 25165824);         //  8 MB  [2,16,2048,64]
  short* Vtb  = (short*)(ws + 33554432);         //  8 MB  [2,16,64,2048]
  short* y_bf = (short*)(ws + 41943040);         //  8 MB  [4096][1024]

  k_prep<<<8192, 256, 0, stream>>>(x, W_attn, W_proj, x_bf, Wt_a, Wt_p);
  k_gemm_qkv<<<dim3(24, 32), 128, 0, stream>>>(x_bf, Wt_a, b_attn, Qb, Kb, Vtb);
  k_attn<<<dim3(32, 32), 256, 0, stream>>>(Qb, Kb, Vtb, y_bf);
  k_gemm_proj<<<dim3(8, 32), 256, 0, stream>>>(y_bf, Wt_p, b_proj, out);
}